// Round 6
// baseline (108.019 us; speedup 1.0000x reference)
//
#include <hip/hip_runtime.h>

// upfirdn2d specialized: up=2, down=1, pad0=2, eff trailing pad 2,
// 4x4 kernel, input (1024, 128, 128) f32 -> output (1024, 256, 256) f32.
//
// Polyphase: output (2r+py, 2c+px) mixes input rows {r-1,r} (py=0) or
// {r,r+1} (py=1), same in x. w[ky][kx] = kernel[3-ky][3-kx] (conv flip).
//
// Each thread: one input ROW-PAIR (r0, r0+1) x 4 cols. Loads rows
// r0-1..r0+2 (4x float4 + 8 independent halo scalars, issued up front),
// computes 4x8 output patch in two passes (o-arrays reused to keep live
// registers ~40 floats; R4 lesson: 62 array floats spilled to scratch).
// Read amplification drops 3x -> 2x vs one-row-per-thread.

typedef float f4 __attribute__((ext_vector_type(4)));

__global__ __launch_bounds__(256) void upfirdn2d_up2_kernel(
    const float* __restrict__ x, const float* __restrict__ kern,
    float* __restrict__ out) {
  constexpr int H = 128, W = 128, OW = 256;

  const int tid = threadIdx.x;
  const int c4  = tid & 31;                             // float4 col 0..31
  const int pr  = ((blockIdx.x & 7) << 3) | (tid >> 5); // row-pair 0..63
  const int img = blockIdx.x >> 3;                      // 0..1023
  const int r0  = pr << 1;                              // first input row

  // Flipped 4x4 kernel weights (uniform -> scalar regs).
  const float w00 = kern[15], w01 = kern[14], w02 = kern[13], w03 = kern[12];
  const float w10 = kern[11], w11 = kern[10], w12 = kern[9],  w13 = kern[8];
  const float w20 = kern[7],  w21 = kern[6],  w22 = kern[5],  w23 = kern[4];
  const float w30 = kern[3],  w31 = kern[2],  w32 = kern[1],  w33 = kern[0];

  const float* xi = x + (size_t)img * H * W;
  const int x0 = c4 << 2;  // first input col of this thread

  // a[0..5] = input cols x0-1 .. x0+4 (zero-padded at image edges)
  float t[6], m[6], b[6], bb[6];

  auto ldrow = [&](int rr, float* a) {
    if (rr >= 0 && rr < H) {
      const float* row = xi + rr * W + x0;
      const f4 v = *reinterpret_cast<const f4*>(row);
      a[0] = (c4 > 0)  ? row[-1] : 0.f;
      a[1] = v.x; a[2] = v.y; a[3] = v.z; a[4] = v.w;
      a[5] = (c4 < 31) ? row[4] : 0.f;
    } else {
      a[0] = a[1] = a[2] = a[3] = a[4] = a[5] = 0.f;
    }
  };
  // Issue all four row loads up front (independent, latency-overlapped).
  ldrow(r0 - 1, t);
  ldrow(r0,     m);
  ldrow(r0 + 1, b);
  ldrow(r0 + 2, bb);

  // One pass: input rows (A=r-1, B=r, C=r+1) -> output rows 2r, 2r+1.
  auto emit = [&](const float* A, const float* B, const float* C,
                  float* orow0) {
    float o0[8], o1[8];
#pragma unroll
    for (int j = 0; j < 4; ++j) {
      o0[2*j]   = w00 * A[j]   + w02 * A[j+1] + w20 * B[j]   + w22 * B[j+1];
      o0[2*j+1] = w01 * A[j+1] + w03 * A[j+2] + w21 * B[j+1] + w23 * B[j+2];
      o1[2*j]   = w10 * B[j]   + w12 * B[j+1] + w30 * C[j]   + w32 * C[j+1];
      o1[2*j+1] = w11 * B[j+1] + w13 * B[j+2] + w31 * C[j+1] + w33 * C[j+2];
    }
    float* orow1 = orow0 + OW;
    f4 v00 = {o0[0], o0[1], o0[2], o0[3]};
    f4 v01 = {o0[4], o0[5], o0[6], o0[7]};
    f4 v10 = {o1[0], o1[1], o1[2], o1[3]};
    f4 v11 = {o1[4], o1[5], o1[6], o1[7]};
    __builtin_nontemporal_store(v00, reinterpret_cast<f4*>(orow0));
    __builtin_nontemporal_store(v01, reinterpret_cast<f4*>(orow0 + 4));
    __builtin_nontemporal_store(v10, reinterpret_cast<f4*>(orow1));
    __builtin_nontemporal_store(v11, reinterpret_cast<f4*>(orow1 + 4));
  };

  float* obase = out + (size_t)img * OW * OW + (size_t)(2 * r0) * OW + 2 * x0;
  emit(t, m, b,  obase);           // output rows 2r0, 2r0+1
  emit(m, b, bb, obase + 2 * OW);  // output rows 2r0+2, 2r0+3
}

extern "C" void kernel_launch(void* const* d_in, const int* in_sizes, int n_in,
                              void* d_out, int out_size, void* d_ws, size_t ws_size,
                              hipStream_t stream) {
  const float* x    = (const float*)d_in[0];
  const float* kern = (const float*)d_in[1];
  float* out        = (float*)d_out;
  // 1024 images x 8 blocks (8 row-pairs x 32 float4-cols per block).
  upfirdn2d_up2_kernel<<<dim3(1024 * 8), dim3(256), 0, stream>>>(x, kern, out);
}